// Round 2
// baseline (337.773 us; speedup 1.0000x reference)
//
#include <hip/hip_runtime.h>
#include <cstdint>
#include <cstddef>

// Problem dims (fixed by reference): x [8,1024,1024] -> M=8192, dim=1024, hidden=4096
#define DIM   1024
#define HID   4096
#define MROWS 8192

typedef __attribute__((ext_vector_type(8))) __bf16 bf16x8;
typedef __attribute__((ext_vector_type(4))) float  f32x4;
typedef __attribute__((ext_vector_type(4))) int    i32x4;

__device__ __forceinline__ unsigned short f2bf(float f) {
  unsigned int u = __float_as_uint(f);
  u += 0x7fffu + ((u >> 16) & 1u);   // round-to-nearest-even
  return (unsigned short)(u >> 16);
}
__device__ __forceinline__ float bf2f(unsigned int lo16) {
  return __uint_as_float(lo16 << 16);
}

// tanh-form GELU: ~7 VALU instrs vs ~25 for erff; deviation from exact ~1e-3.
__device__ __forceinline__ float fast_gelu(float v) {
  float u = v * (0.79788456080286536f + 0.035677408136300125f * v * v);
  float e = __builtin_amdgcn_exp2f(u * 2.8853900817779268f);   // exp(2u)
  float r = __builtin_amdgcn_rcpf(e + 1.0f);
  return v - v * r;   // = v * e/(e+1) = 0.5 v (1+tanh(u))
}

// ---- async global->LDS, 16B per lane (m97 pattern) ----
__device__ __forceinline__ void gld16(const void* g, void* l) {
  auto* gp = reinterpret_cast<__attribute__((address_space(1))) unsigned int*>(
      reinterpret_cast<uintptr_t>(g));
  auto* lp = reinterpret_cast<__attribute__((address_space(3))) unsigned int*>(
      reinterpret_cast<uintptr_t>(l));
  __builtin_amdgcn_global_load_lds(gp, lp, 16, 0, 0);
}

// ---- wave reduce (two values), 64 lanes, shuffle-only ----
__device__ __forceinline__ void wave_reduce2(float& a, float& b) {
#pragma unroll
  for (int off = 32; off > 0; off >>= 1) {
    a += __shfl_xor(a, off, 64);
    b += __shfl_xor(b, off, 64);
  }
}
__device__ __forceinline__ float wave_reduce_max(float m) {
#pragma unroll
  for (int off = 32; off > 0; off >>= 1) m = fmaxf(m, __shfl_xor(m, off, 64));
  return m;
}

// ---- block reduce (two values), 256 threads = 4 waves ----
__device__ __forceinline__ void block_reduce2(float& a, float& b, int tid) {
  __shared__ float red[8];
  __syncthreads();
  wave_reduce2(a, b);
  if ((tid & 63) == 0) { red[tid >> 6] = a; red[4 + (tid >> 6)] = b; }
  __syncthreads();
  a = red[0] + red[1] + red[2] + red[3];
  b = red[4] + red[5] + red[6] + red[7];
}

// ---- prep: |w| partial sums AND LN1(+i8 quant), one dispatch ----
__global__ __launch_bounds__(256)
void prep_kernel(const float* __restrict__ w1, const float* __restrict__ w2,
                 float* __restrict__ part,
                 const float* __restrict__ x, const float* __restrict__ g,
                 const float* __restrict__ b, unsigned int* __restrict__ xn8,
                 float* __restrict__ invs) {
  int tid = threadIdx.x;
  int bid = blockIdx.x;
  if (bid < 2048) {
    const float* w = (bid < 1024) ? w1 : w2;
    int blk = bid & 1023;
    const float4* base = (const float4*)w + (size_t)blk * 1024;
    float s = 0.f;
#pragma unroll
    for (int i = 0; i < 4; ++i) {
      float4 v = base[tid + i * 256];
      s += fabsf(v.x) + fabsf(v.y) + fabsf(v.z) + fabsf(v.w);
    }
#pragma unroll
    for (int off = 32; off > 0; off >>= 1) s += __shfl_xor(s, off, 64);
    __shared__ float red[4];
    if ((tid & 63) == 0) red[tid >> 6] = s;
    __syncthreads();
    if (tid == 0) part[bid] = red[0] + red[1] + red[2] + red[3];
  } else {
    const int row  = (bid - 2048) * 4 + (tid >> 6);
    const int lane = tid & 63;
    const float4* xr = (const float4*)(x + (size_t)row * DIM);
    const float4* g4 = (const float4*)g;
    const float4* b4 = (const float4*)b;
    float4 v[4];
    float s = 0.f, ss = 0.f;
#pragma unroll
    for (int p = 0; p < 4; ++p) {
      v[p] = xr[lane + 64 * p];
      s  += v[p].x + v[p].y + v[p].z + v[p].w;
      ss += v[p].x * v[p].x + v[p].y * v[p].y + v[p].z * v[p].z + v[p].w * v[p].w;
    }
    wave_reduce2(s, ss);
    float mu  = s * (1.0f / DIM);
    float var = ss * (1.0f / DIM) - mu * mu;
    float rs  = rsqrtf(var + 1e-5f);
    float n[4][4];
    float amax = 0.f;
#pragma unroll
    for (int p = 0; p < 4; ++p) {
      float4 gg = g4[lane + 64 * p];
      float4 bb = b4[lane + 64 * p];
      n[p][0] = (v[p].x - mu) * rs * gg.x + bb.x;
      n[p][1] = (v[p].y - mu) * rs * gg.y + bb.y;
      n[p][2] = (v[p].z - mu) * rs * gg.z + bb.z;
      n[p][3] = (v[p].w - mu) * rs * gg.w + bb.w;
#pragma unroll
      for (int c = 0; c < 4; ++c) amax = fmaxf(amax, fabsf(n[p][c]));
    }
    amax = wave_reduce_max(amax);
    float sc, iv;
    if (amax < 1e-20f) { sc = 0.f; iv = 0.f; }
    else               { sc = 127.0f / amax; iv = amax * (1.0f / 127.0f); }
    if (lane == 0) invs[row] = iv;
    unsigned int* dst = xn8 + (size_t)row * 256;   // 1024 i8 = 256 u32 per row
#pragma unroll
    for (int p = 0; p < 4; ++p) {
      unsigned r = 0;
#pragma unroll
      for (int c = 0; c < 4; ++c) {
        int q = (int)rintf(n[p][c] * sc);
        r |= ((unsigned)q & 0xffu) << (8 * c);
      }
      dst[lane + 64 * p] = r;
    }
  }
}

// ---- ternary quantize + folded-LN2 weight vectors ----
__global__ __launch_bounds__(256)
void quant_kernel(const float* __restrict__ part,
                  const float* __restrict__ w1, unsigned int* __restrict__ q1,
                  const float* __restrict__ w2, unsigned short* __restrict__ q2,
                  const float* __restrict__ g2, const float* __restrict__ b2,
                  const float* __restrict__ bias2,
                  float* __restrict__ Sg, float* __restrict__ Cb,
                  float* __restrict__ scal) {
  int bid = blockIdx.x, tid = threadIdx.x;
  const int lane = tid & 63;
  const float4* psrc = (const float4*)(part + ((bid < 512) ? 0 : 1024));
  float a = 0.f, dummy = 0.f;
#pragma unroll
  for (int p = 0; p < 4; ++p) {
    float4 pv = psrc[lane + 64 * p];
    a += pv.x + pv.y + pv.z + pv.w;
  }
  wave_reduce2(a, dummy);
  float mean = fmaxf(a * (1.0f / 4194304.0f), 1e-5f);
  float sc = 1.0f / mean;

  if (bid < 512) {
    if (bid == 0 && tid == 0) scal[0] = mean;
    const int n4 = 1048576;
    int i = bid * 256 + tid;
    for (; i < n4; i += 512 * 256) {
      float4 v = ((const float4*)w1)[i];
      int t0 = (int)fminf(fmaxf(rintf(v.x * sc), -1.f), 1.f);
      int t1 = (int)fminf(fmaxf(rintf(v.y * sc), -1.f), 1.f);
      int t2 = (int)fminf(fmaxf(rintf(v.z * sc), -1.f), 1.f);
      int t3 = (int)fminf(fmaxf(rintf(v.w * sc), -1.f), 1.f);
      unsigned r = ((unsigned)t0 & 0xffu) | (((unsigned)t1 & 0xffu) << 8) |
                   (((unsigned)t2 & 0xffu) << 16) | (((unsigned)t3 & 0xffu) << 24);
      q1[i] = r;
    }
  } else {
    const int d = bid - 512;
    if (d == 0 && tid == 0) scal[1] = mean;
    const float4* wr = (const float4*)(w2 + (size_t)d * HID);
    const float4* g4 = (const float4*)g2;
    const float4* b4 = (const float4*)b2;
    uint2* qr = (uint2*)(q2 + (size_t)d * HID);
    float s1 = 0.f, s2 = 0.f;
#pragma unroll
    for (int i = 0; i < 4; ++i) {
      int idx = tid + 256 * i;
      float4 wv = wr[idx], gv = g4[idx], bv = b4[idx];
      float t0 = fminf(fmaxf(rintf(wv.x * sc), -1.f), 1.f);
      float t1 = fminf(fmaxf(rintf(wv.y * sc), -1.f), 1.f);
      float t2 = fminf(fmaxf(rintf(wv.z * sc), -1.f), 1.f);
      float t3 = fminf(fmaxf(rintf(wv.w * sc), -1.f), 1.f);
      s1 += gv.x * t0 + gv.y * t1 + gv.z * t2 + gv.w * t3;
      s2 += bv.x * t0 + bv.y * t1 + bv.z * t2 + bv.w * t3;
      uint2 r;
      r.x = (unsigned)f2bf(t0 * gv.x) | ((unsigned)f2bf(t1 * gv.y) << 16);
      r.y = (unsigned)f2bf(t2 * gv.z) | ((unsigned)f2bf(t3 * gv.w) << 16);
      qr[idx] = r;
    }
    block_reduce2(s1, s2, tid);
    if (tid == 0) {
      Sg[d] = mean * s1;
      Cb[d] = mean * s2 + bias2[d];
    }
  }
}

// ---- row stats of h (read-only) -> per-row (a_m, b_m) for folded LN2 ----
__global__ __launch_bounds__(256)
void rowstats_kernel(const unsigned short* __restrict__ h,
                     const float* __restrict__ meanp,
                     float2* __restrict__ murs) {
  const int row  = blockIdx.x * 4 + (threadIdx.x >> 6);
  const int lane = threadIdx.x & 63;
  const uint4* hr = (const uint4*)(h + (size_t)row * HID);
  float s = 0.f, ss = 0.f;
#pragma unroll
  for (int p = 0; p < 8; ++p) {
    uint4 pk = hr[lane + 64 * p];
    const unsigned int* pu = (const unsigned int*)&pk;
#pragma unroll
    for (int j = 0; j < 4; ++j) {
      float lo = bf2f(pu[j] & 0xffffu);
      float hi = __uint_as_float(pu[j] & 0xffff0000u);
      s += lo + hi; ss += lo * lo + hi * hi;
    }
  }
  wave_reduce2(s, ss);
  if (lane == 0) {
    float mu  = s * (1.0f / HID);
    float var = ss * (1.0f / HID) - mu * mu;
    float rs  = rsqrtf(var + 1e-5f);
    murs[row] = make_float2(rs * meanp[1], -rs * mu);
  }
}

// ---- GEMM1 (i8): h[m,n] = gelu( (sum_k x8[m,k]*t8[n,k]) * mean1*invs_m + b1[n] )
__global__ __launch_bounds__(256)
void gemm1_i8(const unsigned char* __restrict__ A,
              const unsigned char* __restrict__ B,
              unsigned short* __restrict__ H,
              const float* __restrict__ wscale_ptr,
              const float* __restrict__ invs,
              const float* __restrict__ bias) {
  __shared__ unsigned char sA[128 * 64];
  __shared__ unsigned char sB[128 * 64];

  const int tid  = threadIdx.x;
  const int lane = tid & 63;
  const int wave = tid >> 6;
  const int wm   = wave & 1;
  const int wn   = wave >> 1;

  const int nbx  = gridDim.x;
  const int id   = blockIdx.y * nbx + blockIdx.x;
  const int xcd  = id & 7;
  const int slot = id >> 3;
  const int bandsPerXcd = gridDim.y >> 3;
  const int band = xcd * bandsPerXcd + slot / nbx;
  const int col  = slot - (slot / nbx) * nbx;
  const int bm   = band * 128;
  const int bn   = col * 128;

  const int csw = ((tid & 3) ^ ((tid >> 3) & 3)) * 16;
  const unsigned char* Ab = A + (size_t)(bm + (tid >> 2)) * 1024 + csw;
  const unsigned char* Bb = B + (size_t)(bn + (tid >> 2)) * 1024 + csw;

  i32x4 acc[4][4] = {};

  const int rowA = (wm * 64 + (lane & 15)) * 64;
  const int rowB = (wn * 64 + (lane & 15)) * 64;
  const int kc = (((lane >> 4) ^ ((lane >> 1) & 3))) * 16;

  for (int k0 = 0; k0 < 1024; k0 += 64) {
    gld16(Ab + k0,              sA + tid * 16);
    gld16(Ab + 64 * 1024 + k0,  sA + 4096 + tid * 16);
    gld16(Bb + k0,              sB + tid * 16);
    gld16(Bb + 64 * 1024 + k0,  sB + 4096 + tid * 16);
    __syncthreads();

    i32x4 af[4], bfr[4];
#pragma unroll
    for (int i = 0; i < 4; ++i) af[i]  = *(const i32x4*)(sA + rowA + i * 1024 + kc);
#pragma unroll
    for (int j = 0; j < 4; ++j) bfr[j] = *(const i32x4*)(sB + rowB + j * 1024 + kc);
#pragma unroll
    for (int i = 0; i < 4; ++i)
#pragma unroll
      for (int j = 0; j < 4; ++j)
        acc[i][j] = __builtin_amdgcn_mfma_i32_16x16x64_i8(af[i], bfr[j], acc[i][j], 0, 0, 0);
    __syncthreads();
  }

  const float wscale = *wscale_ptr;
  float bv[4];
#pragma unroll
  for (int j = 0; j < 4; ++j) bv[j] = bias[bn + wn * 64 + j * 16 + (lane & 15)];
#pragma unroll
  for (int i = 0; i < 4; ++i) {
    const int m0 = bm + wm * 64 + i * 16 + ((lane >> 4) << 2);
    float asc[4];
#pragma unroll
    for (int r = 0; r < 4; ++r) asc[r] = wscale * invs[m0 + r];
#pragma unroll
    for (int j = 0; j < 4; ++j) {
      const int n = bn + wn * 64 + j * 16 + (lane & 15);
#pragma unroll
      for (int r = 0; r < 4; ++r) {
        float v = fast_gelu((float)acc[i][j][r] * asc[r] + bv[j]);
        H[(size_t)(m0 + r) * HID + n] = f2bf(v);
      }
    }
  }
}

// ---- GEMM2, A-in-registers (reg-staged) version ----
// Post-mortem R1: 8-phase gave nothing because the kernel is LDS-BW-bound:
// per K-tile/CU, MFMA=1242cy but LDS=176KB=1400-2100cy (reads 128K + stage 48K).
// Fix the RATIO, not the schedule: A's MFMA fragment (row=..+(lane&15),
// kchunk=(lane>>4)*8) is directly loadable from row-major global -> A never
// touches LDS. LDS/K-tile drops to 80KB (B read 64K + B stage 16K) << MFMA.
// A is issued 2x per block (wn pair shares rows) but HBM is at 17% and L2
// (34.5TB/s) serves re-reads. One barrier + one vmcnt(0) per K-tile; loads
// issue early / drain late, so the drain waits ~0 (MFMA covers L2 latency).
// A-load waits are left to the compiler's exact vmcnt tracking (robust);
// only the gld_lds->ds_read hazard is hand-fenced (verified pattern).
__global__ __launch_bounds__(512, 2)
void gemm2_areg(const unsigned short* __restrict__ A,
                const unsigned short* __restrict__ B,
                float* __restrict__ C,
                const float2* __restrict__ murs,
                const float* __restrict__ Sg,
                const float* __restrict__ Cb) {
  __shared__ unsigned short sB[2][128 * 64];   // 32 KiB total

  const int tid  = threadIdx.x;
  const int lane = tid & 63;
  const int wave = tid >> 6;
  const int wm   = wave >> 1;    // 0..3
  const int wn   = wave & 1;     // 0..1

  // XCD-aware remap: 256 blocks (32 bands x 8 cols), 4 bands/XCD. Bijective.
  const int id   = blockIdx.y * 8 + blockIdx.x;
  const int xcd  = id & 7;
  const int slot = id >> 3;
  const int band = xcd * 4 + (slot >> 3);
  const int col  = slot & 7;
  const int bm   = band * 256;
  const int bn   = col * 128;

  // B staging: linear LDS dest + pre-swizzled global source (rule #21)
  const int csw = ((tid & 7) ^ ((tid >> 3) & 7)) << 3;     // elements
  const unsigned short* Bb = B + (size_t)(bn + (tid >> 3)) * 4096 + csw;
  char* lb0 = (char*)&sB[0][0] + tid * 16;
  char* lb1 = (char*)&sB[1][0] + tid * 16;

  // B fragment reads: row = wn*64 + j*16 + (lane&15); phys chunk = log ^ (lane&7)
  const int rowBb = (wn * 64 + (lane & 15)) * 128;   // bytes
  const int hi    = lane >> 4;
  const int ck0   = ((hi)     ^ (lane & 7)) << 4;    // k-slice 0, bytes
  const int ck1   = ((hi + 4) ^ (lane & 7)) << 4;    // k-slice 1

  // A direct-to-reg: lane reads A[bm+wm*64+i*16+(lane&15)][k0+s*32+(lane>>4)*8]
  const unsigned short* aBase =
      A + (size_t)(bm + wm * 64 + (lane & 15)) * 4096 + (hi << 3);

  f32x4 acc[4][4] = {};
  bf16x8 afA[4][2], afB[4][2];   // double-buffered A fragments (static-indexed)

  // ---- prologue: B(0)->buf0; A(0)->afA; drain; barrier
#pragma unroll
  for (int i = 0; i < 2; ++i) gld16(Bb + (size_t)i * 262144, lb0 + i * 8192);
#pragma unroll
  for (int i = 0; i < 4; ++i)
#pragma unroll
    for (int s = 0; s < 2; ++s)
      afA[i][s] = *(const bf16x8*)(aBase + i * 65536 + s * 32);
  asm volatile("s_waitcnt vmcnt(0)" ::: "memory");
  __builtin_amdgcn_s_barrier();

  // One half-iteration: stage B(next)->LB_NXT, prefetch A(next)->AF_NXT,
  // ds_read bfr from buf CUR, 32 MFMA on AF_CUR, drain, barrier.
#define HALF_ITER(AF_CUR, AF_NXT, CUR, LB_NXT, KNXT)                            \
  do {                                                                          \
    const size_t kn = (KNXT);                                                   \
    _Pragma("unroll") for (int i = 0; i < 2; ++i)                               \
      gld16(Bb + (size_t)i * 262144 + kn, (LB_NXT) + i * 8192);                 \
    _Pragma("unroll") for (int i = 0; i < 4; ++i)                               \
    _Pragma("unroll") for (int s = 0; s < 2; ++s)                               \
      AF_NXT[i][s] = *(const bf16x8*)(aBase + i * 65536 + kn + s * 32);         \
    bf16x8 bfr[4][2];                                                           \
    const char* bp = (const char*)&sB[0][0] + (CUR) * 16384;                    \
    _Pragma("unroll") for (int j = 0; j < 4; ++j) {                             \
      bfr[j][0] = *(const bf16x8*)(bp + rowBb + j * 2048 + ck0);                \
      bfr[j][1] = *(const bf16x8*)(bp + rowBb + j * 2048 + ck1);                \
    }                                                                           \
    __builtin_amdgcn_s_setprio(1);                                              \
    _Pragma("unroll") for (int i2 = 0; i2 < 4; ++i2)                            \
    _Pragma("unroll") for (int j2 = 0; j2 < 4; ++j2)                            \
    _Pragma("unroll") for (int kk = 0; kk < 2; ++kk)                            \
      acc[i2][j2] = __builtin_amdgcn_mfma_f32_16x16x32_bf16(                    \
          AF_CUR[i2][kk], bfr[j2][kk], acc[i2][j2], 0, 0, 0);                   \
    __builtin_amdgcn_s_setprio(0);                                              \
    asm volatile("s_waitcnt vmcnt(0)" ::: "memory");                            \
    __builtin_amdgcn_s_barrier();                                               \
  } while (0)

  for (int t = 0; t < 64; t += 2) {
    // tile t (even): B(t) in buf0, A(t) in afA. Prefetch t+1 (always valid).
    HALF_ITER(afA, afB, 0, lb1, (size_t)(t + 1) * 64);
    // tile t+1 (odd): prefetch t+2, clamped to 0 on the last iter (junk,
    // lands in buf0 / afA which are never read again).
    HALF_ITER(afB, afA, 1, lb0, (t + 2 < 64) ? (size_t)(t + 2) * 64 : 0);
  }
#undef HALF_ITER

  // ---- epilogue: out = a_m*acc + b_m*Sg[n] + Cb[n]
  float sg[4], cb[4];
#pragma unroll
  for (int j = 0; j < 4; ++j) {
    const int n = bn + wn * 64 + j * 16 + (lane & 15);
    sg[j] = Sg[n];
    cb[j] = Cb[n];
  }
#pragma unroll
  for (int i = 0; i < 4; ++i) {
    const int m0 = bm + wm * 64 + i * 16 + (hi << 2);
#pragma unroll
    for (int r = 0; r < 4; ++r) {
      float2 ab = murs[m0 + r];
#pragma unroll
      for (int j = 0; j < 4; ++j) {
        const int n = bn + wn * 64 + j * 16 + (lane & 15);
        C[(size_t)(m0 + r) * 1024 + n] = ab.x * acc[i][j][r] + ab.y * sg[j] + cb[j];
      }
    }
  }
}

extern "C" void kernel_launch(void* const* d_in, const int* in_sizes, int n_in,
                              void* d_out, int out_size, void* d_ws, size_t ws_size,
                              hipStream_t stream) {
  const float* x     = (const float*)d_in[0];
  const float* g1    = (const float*)d_in[1];
  const float* b1v   = (const float*)d_in[2];
  const float* w1    = (const float*)d_in[3];
  const float* bias1 = (const float*)d_in[4];
  const float* g2    = (const float*)d_in[5];
  const float* b2v   = (const float*)d_in[6];
  const float* w2    = (const float*)d_in[7];
  const float* bias2 = (const float*)d_in[8];
  float* out = (float*)d_out;

  char* ws = (char*)d_ws;
  float* scal          = (float*)ws;                      // [0]=mean|w1| [1]=mean|w2|
  float* part          = (float*)(ws + 64);               // 2048 partials
  float* invs          = (float*)(ws + 16384);            // 8192 per-row dequant (32 KB)
  unsigned int* q1     = (unsigned int*)(ws + 65536);     // 4096x1024 i8 = 4 MB
  unsigned short* q2   = (unsigned short*)(ws + 65536 + 4194304);  // 8 MB bf16
  unsigned int* xn8    = (unsigned int*)((char*)q2 + 8388608);     // 8192x1024 i8 = 8 MB
  unsigned short* h    = (unsigned short*)((char*)xn8 + 8388608);  // 64 MB bf16
  float2* murs         = (float2*)((char*)h + 67108864);  // 8192 x {a_m,b_m}
  float* Sg            = (float*)(murs + 8192);           // 1024
  float* Cb            = Sg + 1024;                       // 1024

  prep_kernel<<<4096, 256, 0, stream>>>(w1, w2, part, x, g1, b1v, xn8, invs);
  quant_kernel<<<1536, 256, 0, stream>>>(part, w1, q1, w2, q2, g2, b2v, bias2, Sg, Cb, scal);
  gemm1_i8<<<dim3(HID / 128, MROWS / 128), 256, 0, stream>>>(
      (const unsigned char*)xn8, (const unsigned char*)q1, h, scal + 0, invs, bias1);
  rowstats_kernel<<<2048, 256, 0, stream>>>(h, scal, murs);
  gemm2_areg<<<dim3(8, 32), 512, 0, stream>>>(h, q2, out, murs, Sg, Cb);
}

// Round 3
// 314.234 us; speedup vs baseline: 1.0749x; 1.0749x over previous
//
#include <hip/hip_runtime.h>
#include <cstdint>
#include <cstddef>

// Problem dims (fixed by reference): x [8,1024,1024] -> M=8192, dim=1024, hidden=4096
#define DIM   1024
#define HID   4096
#define MROWS 8192

typedef __attribute__((ext_vector_type(8))) __bf16 bf16x8;
typedef __attribute__((ext_vector_type(4))) float  f32x4;
typedef __attribute__((ext_vector_type(4))) int    i32x4;

__device__ __forceinline__ unsigned short f2bf(float f) {
  unsigned int u = __float_as_uint(f);
  u += 0x7fffu + ((u >> 16) & 1u);   // round-to-nearest-even
  return (unsigned short)(u >> 16);
}
__device__ __forceinline__ float bf2f(unsigned int lo16) {
  return __uint_as_float(lo16 << 16);
}

// tanh-form GELU: ~7 VALU instrs vs ~25 for erff; deviation from exact ~1e-3.
__device__ __forceinline__ float fast_gelu(float v) {
  float u = v * (0.79788456080286536f + 0.035677408136300125f * v * v);
  float e = __builtin_amdgcn_exp2f(u * 2.8853900817779268f);   // exp(2u)
  float r = __builtin_amdgcn_rcpf(e + 1.0f);
  return v - v * r;   // = v * e/(e+1) = 0.5 v (1+tanh(u))
}

// ---- async global->LDS, 16B per lane (m97 pattern) ----
__device__ __forceinline__ void gld16(const void* g, void* l) {
  auto* gp = reinterpret_cast<__attribute__((address_space(1))) unsigned int*>(
      reinterpret_cast<uintptr_t>(g));
  auto* lp = reinterpret_cast<__attribute__((address_space(3))) unsigned int*>(
      reinterpret_cast<uintptr_t>(l));
  __builtin_amdgcn_global_load_lds(gp, lp, 16, 0, 0);
}

// ---- wave reduce (two values), 64 lanes, shuffle-only ----
__device__ __forceinline__ void wave_reduce2(float& a, float& b) {
#pragma unroll
  for (int off = 32; off > 0; off >>= 1) {
    a += __shfl_xor(a, off, 64);
    b += __shfl_xor(b, off, 64);
  }
}
__device__ __forceinline__ float wave_reduce_max(float m) {
#pragma unroll
  for (int off = 32; off > 0; off >>= 1) m = fmaxf(m, __shfl_xor(m, off, 64));
  return m;
}

// ---- block reduce (two values), 256 threads = 4 waves ----
__device__ __forceinline__ void block_reduce2(float& a, float& b, int tid) {
  __shared__ float red[8];
  __syncthreads();
  wave_reduce2(a, b);
  if ((tid & 63) == 0) { red[tid >> 6] = a; red[4 + (tid >> 6)] = b; }
  __syncthreads();
  a = red[0] + red[1] + red[2] + red[3];
  b = red[4] + red[5] + red[6] + red[7];
}

// ---- prep: |w| partial sums AND LN1(+i8 quant), one dispatch ----
__global__ __launch_bounds__(256)
void prep_kernel(const float* __restrict__ w1, const float* __restrict__ w2,
                 float* __restrict__ part,
                 const float* __restrict__ x, const float* __restrict__ g,
                 const float* __restrict__ b, unsigned int* __restrict__ xn8,
                 float* __restrict__ invs) {
  int tid = threadIdx.x;
  int bid = blockIdx.x;
  if (bid < 2048) {
    const float* w = (bid < 1024) ? w1 : w2;
    int blk = bid & 1023;
    const float4* base = (const float4*)w + (size_t)blk * 1024;
    float s = 0.f;
#pragma unroll
    for (int i = 0; i < 4; ++i) {
      float4 v = base[tid + i * 256];
      s += fabsf(v.x) + fabsf(v.y) + fabsf(v.z) + fabsf(v.w);
    }
#pragma unroll
    for (int off = 32; off > 0; off >>= 1) s += __shfl_xor(s, off, 64);
    __shared__ float red[4];
    if ((tid & 63) == 0) red[tid >> 6] = s;
    __syncthreads();
    if (tid == 0) part[bid] = red[0] + red[1] + red[2] + red[3];
  } else {
    const int row  = (bid - 2048) * 4 + (tid >> 6);
    const int lane = tid & 63;
    const float4* xr = (const float4*)(x + (size_t)row * DIM);
    const float4* g4 = (const float4*)g;
    const float4* b4 = (const float4*)b;
    float4 v[4];
    float s = 0.f, ss = 0.f;
#pragma unroll
    for (int p = 0; p < 4; ++p) {
      v[p] = xr[lane + 64 * p];
      s  += v[p].x + v[p].y + v[p].z + v[p].w;
      ss += v[p].x * v[p].x + v[p].y * v[p].y + v[p].z * v[p].z + v[p].w * v[p].w;
    }
    wave_reduce2(s, ss);
    float mu  = s * (1.0f / DIM);
    float var = ss * (1.0f / DIM) - mu * mu;
    float rs  = rsqrtf(var + 1e-5f);
    float n[4][4];
    float amax = 0.f;
#pragma unroll
    for (int p = 0; p < 4; ++p) {
      float4 gg = g4[lane + 64 * p];
      float4 bb = b4[lane + 64 * p];
      n[p][0] = (v[p].x - mu) * rs * gg.x + bb.x;
      n[p][1] = (v[p].y - mu) * rs * gg.y + bb.y;
      n[p][2] = (v[p].z - mu) * rs * gg.z + bb.z;
      n[p][3] = (v[p].w - mu) * rs * gg.w + bb.w;
#pragma unroll
      for (int c = 0; c < 4; ++c) amax = fmaxf(amax, fabsf(n[p][c]));
    }
    amax = wave_reduce_max(amax);
    float sc, iv;
    if (amax < 1e-20f) { sc = 0.f; iv = 0.f; }
    else               { sc = 127.0f / amax; iv = amax * (1.0f / 127.0f); }
    if (lane == 0) invs[row] = iv;
    unsigned int* dst = xn8 + (size_t)row * 256;   // 1024 i8 = 256 u32 per row
#pragma unroll
    for (int p = 0; p < 4; ++p) {
      unsigned r = 0;
#pragma unroll
      for (int c = 0; c < 4; ++c) {
        int q = (int)rintf(n[p][c] * sc);
        r |= ((unsigned)q & 0xffu) << (8 * c);
      }
      dst[lane + 64 * p] = r;
    }
  }
}

// ---- ternary quantize + folded-LN2 weight vectors ----
__global__ __launch_bounds__(256)
void quant_kernel(const float* __restrict__ part,
                  const float* __restrict__ w1, unsigned int* __restrict__ q1,
                  const float* __restrict__ w2, unsigned short* __restrict__ q2,
                  const float* __restrict__ g2, const float* __restrict__ b2,
                  const float* __restrict__ bias2,
                  float* __restrict__ Sg, float* __restrict__ Cb,
                  float* __restrict__ scal) {
  int bid = blockIdx.x, tid = threadIdx.x;
  const int lane = tid & 63;
  const float4* psrc = (const float4*)(part + ((bid < 512) ? 0 : 1024));
  float a = 0.f, dummy = 0.f;
#pragma unroll
  for (int p = 0; p < 4; ++p) {
    float4 pv = psrc[lane + 64 * p];
    a += pv.x + pv.y + pv.z + pv.w;
  }
  wave_reduce2(a, dummy);
  float mean = fmaxf(a * (1.0f / 4194304.0f), 1e-5f);
  float sc = 1.0f / mean;

  if (bid < 512) {
    if (bid == 0 && tid == 0) scal[0] = mean;
    const int n4 = 1048576;
    int i = bid * 256 + tid;
    for (; i < n4; i += 512 * 256) {
      float4 v = ((const float4*)w1)[i];
      int t0 = (int)fminf(fmaxf(rintf(v.x * sc), -1.f), 1.f);
      int t1 = (int)fminf(fmaxf(rintf(v.y * sc), -1.f), 1.f);
      int t2 = (int)fminf(fmaxf(rintf(v.z * sc), -1.f), 1.f);
      int t3 = (int)fminf(fmaxf(rintf(v.w * sc), -1.f), 1.f);
      unsigned r = ((unsigned)t0 & 0xffu) | (((unsigned)t1 & 0xffu) << 8) |
                   (((unsigned)t2 & 0xffu) << 16) | (((unsigned)t3 & 0xffu) << 24);
      q1[i] = r;
    }
  } else {
    const int d = bid - 512;
    if (d == 0 && tid == 0) scal[1] = mean;
    const float4* wr = (const float4*)(w2 + (size_t)d * HID);
    const float4* g4 = (const float4*)g2;
    const float4* b4 = (const float4*)b2;
    uint2* qr = (uint2*)(q2 + (size_t)d * HID);
    float s1 = 0.f, s2 = 0.f;
#pragma unroll
    for (int i = 0; i < 4; ++i) {
      int idx = tid + 256 * i;
      float4 wv = wr[idx], gv = g4[idx], bv = b4[idx];
      float t0 = fminf(fmaxf(rintf(wv.x * sc), -1.f), 1.f);
      float t1 = fminf(fmaxf(rintf(wv.y * sc), -1.f), 1.f);
      float t2 = fminf(fmaxf(rintf(wv.z * sc), -1.f), 1.f);
      float t3 = fminf(fmaxf(rintf(wv.w * sc), -1.f), 1.f);
      s1 += gv.x * t0 + gv.y * t1 + gv.z * t2 + gv.w * t3;
      s2 += bv.x * t0 + bv.y * t1 + bv.z * t2 + bv.w * t3;
      uint2 r;
      r.x = (unsigned)f2bf(t0 * gv.x) | ((unsigned)f2bf(t1 * gv.y) << 16);
      r.y = (unsigned)f2bf(t2 * gv.z) | ((unsigned)f2bf(t3 * gv.w) << 16);
      qr[idx] = r;
    }
    block_reduce2(s1, s2, tid);
    if (tid == 0) {
      Sg[d] = mean * s1;
      Cb[d] = mean * s2 + bias2[d];
    }
  }
}

// ---- GEMM1 (i8) v2: double-buffered LDS, ONE barrier + ONE vmcnt per K-tile;
// row-stats (sum, sumsq of f32 gelu output) fused into the epilogue via
// 16-lane shuffle reduce + 2 atomicAdds per row-segment. Replaces the
// rowstats kernel's 64MB h re-read.
__global__ __launch_bounds__(256)
void gemm1_i8(const unsigned char* __restrict__ A,
              const unsigned char* __restrict__ B,
              unsigned short* __restrict__ H,
              const float* __restrict__ wscale_ptr,
              const float* __restrict__ invs,
              const float* __restrict__ bias,
              float* __restrict__ sbuf) {
  __shared__ unsigned char sA[2][128 * 64];
  __shared__ unsigned char sB[2][128 * 64];

  const int tid  = threadIdx.x;
  const int lane = tid & 63;
  const int wave = tid >> 6;
  const int wm   = wave & 1;
  const int wn   = wave >> 1;

  const int nbx  = gridDim.x;
  const int id   = blockIdx.y * nbx + blockIdx.x;
  const int xcd  = id & 7;
  const int slot = id >> 3;
  const int bandsPerXcd = gridDim.y >> 3;
  const int band = xcd * bandsPerXcd + slot / nbx;
  const int col  = slot - (slot / nbx) * nbx;
  const int bm   = band * 128;
  const int bn   = col * 128;

  const int csw = ((tid & 3) ^ ((tid >> 3) & 3)) * 16;
  const unsigned char* Ab = A + (size_t)(bm + (tid >> 2)) * 1024 + csw;
  const unsigned char* Bb = B + (size_t)(bn + (tid >> 2)) * 1024 + csw;

  i32x4 acc[4][4] = {};

  const int rowA = (wm * 64 + (lane & 15)) * 64;
  const int rowB = (wn * 64 + (lane & 15)) * 64;
  const int kc = (((lane >> 4) ^ ((lane >> 1) & 3))) * 16;

  // prologue: stage tile 0 -> buf0
  gld16(Ab,             (char*)&sA[0][0] + tid * 16);
  gld16(Ab + 64 * 1024, (char*)&sA[0][0] + 4096 + tid * 16);
  gld16(Bb,             (char*)&sB[0][0] + tid * 16);
  gld16(Bb + 64 * 1024, (char*)&sB[0][0] + 4096 + tid * 16);
  asm volatile("s_waitcnt vmcnt(0)" ::: "memory");
  __builtin_amdgcn_s_barrier();

  for (int t = 0; t < 16; ++t) {
    const int cur = t & 1;
    const size_t kn = (t + 1 < 16) ? (size_t)(t + 1) * 64 : 0;   // clamp = junk, never read
    // 1. issue stage(t+1) -> buf^1 (its old content was consumed before last barrier)
    gld16(Ab + kn,             (char*)&sA[cur ^ 1][0] + tid * 16);
    gld16(Ab + 64 * 1024 + kn, (char*)&sA[cur ^ 1][0] + 4096 + tid * 16);
    gld16(Bb + kn,             (char*)&sB[cur ^ 1][0] + tid * 16);
    gld16(Bb + 64 * 1024 + kn, (char*)&sB[cur ^ 1][0] + 4096 + tid * 16);
    // 2. fragment reads from buf cur (compiler inserts counted lgkm waits)
    const unsigned char* a = &sA[cur][0];
    const unsigned char* b = &sB[cur][0];
    i32x4 af[4], bfr[4];
#pragma unroll
    for (int i = 0; i < 4; ++i) af[i]  = *(const i32x4*)(a + rowA + i * 1024 + kc);
#pragma unroll
    for (int j = 0; j < 4; ++j) bfr[j] = *(const i32x4*)(b + rowB + j * 1024 + kc);
    // 3. MFMA
    __builtin_amdgcn_s_setprio(1);
#pragma unroll
    for (int i = 0; i < 4; ++i)
#pragma unroll
      for (int j = 0; j < 4; ++j)
        acc[i][j] = __builtin_amdgcn_mfma_i32_16x16x64_i8(af[i], bfr[j], acc[i][j], 0, 0, 0);
    __builtin_amdgcn_s_setprio(0);
    // 4. stage(t+1) landed (waited ~0: MFMA span covered latency); next tile may read
    asm volatile("s_waitcnt vmcnt(0)" ::: "memory");
    __builtin_amdgcn_s_barrier();
  }

  const float wscale = *wscale_ptr;
  float bv[4];
#pragma unroll
  for (int j = 0; j < 4; ++j) bv[j] = bias[bn + wn * 64 + j * 16 + (lane & 15)];
#pragma unroll
  for (int i = 0; i < 4; ++i) {
    const int m0 = bm + wm * 64 + i * 16 + ((lane >> 4) << 2);
    float asc[4];
#pragma unroll
    for (int r = 0; r < 4; ++r) asc[r] = wscale * invs[m0 + r];
#pragma unroll
    for (int r = 0; r < 4; ++r) {
      float s = 0.f, ss = 0.f;
#pragma unroll
      for (int j = 0; j < 4; ++j) {
        const int n = bn + wn * 64 + j * 16 + (lane & 15);
        float v = fast_gelu((float)acc[i][j][r] * asc[r] + bv[j]);
        H[(size_t)(m0 + r) * HID + n] = f2bf(v);
        s += v; ss += v * v;
      }
      // reduce across the 16 lanes of this hi-group (offsets < 16 stay in group)
#pragma unroll
      for (int off = 1; off < 16; off <<= 1) {
        s  += __shfl_xor(s, off, 64);
        ss += __shfl_xor(ss, off, 64);
      }
      if ((lane & 15) == 0) {
        atomicAdd(&sbuf[2 * (m0 + r)],     s);
        atomicAdd(&sbuf[2 * (m0 + r) + 1], ss);
      }
    }
  }
}

// ---- finalize per-row (a_m, b_m) from fused sums ----
__global__ __launch_bounds__(256)
void murs_fin(const float* __restrict__ sbuf, const float* __restrict__ meanp,
              float2* __restrict__ murs) {
  const int row = blockIdx.x * 256 + threadIdx.x;
  float2 sv = ((const float2*)sbuf)[row];
  float mu  = sv.x * (1.0f / HID);
  float var = sv.y * (1.0f / HID) - mu * mu;
  float rs  = rsqrtf(var + 1e-5f);
  murs[row] = make_float2(rs * meanp[1], -rs * mu);
}

// ---- GEMM2 v3: dbuf bf16, ONE barrier + ONE vmcnt(0) per K-tile ----
// Post-mortem R1/R2: MFMA ~1240cy/CU/tile, LDS reads ~1540cy, stage ~375cy;
// R1's 8-sync-point phases serialized them (2850cy). v3: issue stage(t+1)
// first (latency under compute), 16 ds_reads, 32 MFMA with compiler-counted
// lgkm waits, vmcnt(0)+barrier at tile end (waits ~0 after the MFMA span).
// Cross-wave skew overlaps LDS pipe with MFMA pipe. Target ~1700-2000cy/tile.
// T1 XCD swizzle + T2 swizzled LDS (pre-swizzled global src, rule #21) kept.
__global__ __launch_bounds__(512, 2)
void gemm2_v3(const unsigned short* __restrict__ A,
              const unsigned short* __restrict__ B,
              float* __restrict__ C,
              const float2* __restrict__ murs,
              const float* __restrict__ Sg,
              const float* __restrict__ Cb) {
  __shared__ unsigned short sA[2][256 * 64];
  __shared__ unsigned short sB[2][128 * 64];

  const int tid  = threadIdx.x;
  const int lane = tid & 63;
  const int wave = tid >> 6;
  const int wm   = wave >> 1;    // 0..3
  const int wn   = wave & 1;     // 0..1

  // XCD-aware remap: 256 blocks (32 bands x 8 cols), 4 bands/XCD. Bijective.
  const int id   = blockIdx.y * 8 + blockIdx.x;
  const int xcd  = id & 7;
  const int slot = id >> 3;
  const int band = xcd * 4 + (slot >> 3);
  const int col  = slot & 7;
  const int bm   = band * 256;
  const int bn   = col * 128;

  // staging: linear LDS dest + pre-swizzled global source (rule #21)
  const int csw = ((tid & 7) ^ ((tid >> 3) & 7)) << 3;     // elements
  const unsigned short* Ab = A + (size_t)(bm + (tid >> 3)) * 4096 + csw;
  const unsigned short* Bb = B + (size_t)(bn + (tid >> 3)) * 4096 + csw;

  // fragment reads: row = wbase + frag*16 + (lane&15); phys chunk = log ^ (lane&7)
  const int rowAb = (wm * 64 + (lane & 15)) * 128;   // bytes
  const int rowBb = (wn * 64 + (lane & 15)) * 128;
  const int hi    = lane >> 4;
  const int ck0   = ((hi)     ^ (lane & 7)) << 4;    // k-slice 0, bytes
  const int ck1   = ((hi + 4) ^ (lane & 7)) << 4;    // k-slice 1

  f32x4 acc[4][4] = {};

  // prologue: stage tile 0 -> buf0
#pragma unroll
  for (int i = 0; i < 4; ++i) gld16(Ab + (size_t)i * 262144, (char*)&sA[0][0] + i * 8192 + tid * 16);
#pragma unroll
  for (int i = 0; i < 2; ++i) gld16(Bb + (size_t)i * 262144, (char*)&sB[0][0] + i * 8192 + tid * 16);
  asm volatile("s_waitcnt vmcnt(0)" ::: "memory");
  __builtin_amdgcn_s_barrier();

  for (int t = 0; t < 64; ++t) {
    const int cur = t & 1;
    const size_t kn = (t + 1 < 64) ? (size_t)(t + 1) * 64 : 0;   // clamp = junk, never read
    // 1. issue stage(t+1) -> buf^1 (consumed before the barrier we just passed)
#pragma unroll
    for (int i = 0; i < 4; ++i)
      gld16(Ab + (size_t)i * 262144 + kn, (char*)&sA[cur ^ 1][0] + i * 8192 + tid * 16);
#pragma unroll
    for (int i = 0; i < 2; ++i)
      gld16(Bb + (size_t)i * 262144 + kn, (char*)&sB[cur ^ 1][0] + i * 8192 + tid * 16);
    // 2. all 16 fragment reads from buf cur
    const char* a = (const char*)&sA[cur][0];
    const char* b = (const char*)&sB[cur][0];
    bf16x8 af[4][2], bfr[4][2];
#pragma unroll
    for (int i = 0; i < 4; ++i) {
      af[i][0] = *(const bf16x8*)(a + rowAb + i * 2048 + ck0);
      af[i][1] = *(const bf16x8*)(a + rowAb + i * 2048 + ck1);
    }
#pragma unroll
    for (int j = 0; j < 4; ++j) {
      bfr[j][0] = *(const bf16x8*)(b + rowBb + j * 2048 + ck0);
      bfr[j][1] = *(const bf16x8*)(b + rowBb + j * 2048 + ck1);
    }
    // 3. 32 MFMA, k-slice 0 cluster first (waits only the first half of reads)
    __builtin_amdgcn_s_setprio(1);
#pragma unroll
    for (int i = 0; i < 4; ++i)
#pragma unroll
      for (int j = 0; j < 4; ++j)
        acc[i][j] = __builtin_amdgcn_mfma_f32_16x16x32_bf16(af[i][0], bfr[j][0], acc[i][j], 0, 0, 0);
#pragma unroll
    for (int i = 0; i < 4; ++i)
#pragma unroll
      for (int j = 0; j < 4; ++j)
        acc[i][j] = __builtin_amdgcn_mfma_f32_16x16x32_bf16(af[i][1], bfr[j][1], acc[i][j], 0, 0, 0);
    __builtin_amdgcn_s_setprio(0);
    // 4. stage(t+1) landed (MFMA span covered latency); release buffers
    asm volatile("s_waitcnt vmcnt(0)" ::: "memory");
    __builtin_amdgcn_s_barrier();
  }

  // ---- epilogue: out = a_m*acc + b_m*Sg[n] + Cb[n]
  float sg[4], cb[4];
#pragma unroll
  for (int j = 0; j < 4; ++j) {
    const int n = bn + wn * 64 + j * 16 + (lane & 15);
    sg[j] = Sg[n];
    cb[j] = Cb[n];
  }
#pragma unroll
  for (int i = 0; i < 4; ++i) {
    const int m0 = bm + wm * 64 + i * 16 + (hi << 2);
#pragma unroll
    for (int r = 0; r < 4; ++r) {
      float2 ab = murs[m0 + r];
#pragma unroll
      for (int j = 0; j < 4; ++j) {
        const int n = bn + wn * 64 + j * 16 + (lane & 15);
        C[(size_t)(m0 + r) * 1024 + n] = ab.x * acc[i][j][r] + ab.y * sg[j] + cb[j];
      }
    }
  }
}

extern "C" void kernel_launch(void* const* d_in, const int* in_sizes, int n_in,
                              void* d_out, int out_size, void* d_ws, size_t ws_size,
                              hipStream_t stream) {
  const float* x     = (const float*)d_in[0];
  const float* g1    = (const float*)d_in[1];
  const float* b1v   = (const float*)d_in[2];
  const float* w1    = (const float*)d_in[3];
  const float* bias1 = (const float*)d_in[4];
  const float* g2    = (const float*)d_in[5];
  const float* b2v   = (const float*)d_in[6];
  const float* w2    = (const float*)d_in[7];
  const float* bias2 = (const float*)d_in[8];
  float* out = (float*)d_out;

  char* ws = (char*)d_ws;
  float* scal          = (float*)ws;                      // [0]=mean|w1| [1]=mean|w2|
  float* part          = (float*)(ws + 64);               // 2048 partials
  float* invs          = (float*)(ws + 16384);            // 8192 per-row dequant (32 KB)
  unsigned int* q1     = (unsigned int*)(ws + 65536);     // 4096x1024 i8 = 4 MB
  unsigned short* q2   = (unsigned short*)(ws + 65536 + 4194304);  // 8 MB bf16
  unsigned int* xn8    = (unsigned int*)((char*)q2 + 8388608);     // 8192x1024 i8 = 8 MB
  unsigned short* h    = (unsigned short*)((char*)xn8 + 8388608);  // 64 MB bf16
  float2* murs         = (float2*)((char*)h + 67108864);  // 8192 x {a_m,b_m}
  float* Sg            = (float*)(murs + 8192);           // 1024
  float* Cb            = Sg + 1024;                       // 1024
  float* sbuf          = Cb + 1024;                       // 8192 x {s, ss} = 64 KB

  hipMemsetAsync(sbuf, 0, MROWS * 2 * sizeof(float), stream);
  prep_kernel<<<4096, 256, 0, stream>>>(w1, w2, part, x, g1, b1v, xn8, invs);
  quant_kernel<<<1536, 256, 0, stream>>>(part, w1, q1, w2, q2, g2, b2v, bias2, Sg, Cb, scal);
  gemm1_i8<<<dim3(HID / 128, MROWS / 128), 256, 0, stream>>>(
      (const unsigned char*)xn8, (const unsigned char*)q1, h, scal + 0, invs, bias1, sbuf);
  murs_fin<<<MROWS / 256, 256, 0, stream>>>(sbuf, scal, murs);
  gemm2_v3<<<dim3(8, 32), 512, 0, stream>>>(h, q2, out, murs, Sg, Cb);
}

// Round 4
// 245.410 us; speedup vs baseline: 1.3764x; 1.2804x over previous
//
#include <hip/hip_runtime.h>
#include <cstdint>
#include <cstddef>

// Problem dims (fixed by reference): x [8,1024,1024] -> M=8192, dim=1024, hidden=4096
#define DIM   1024
#define HID   4096
#define MROWS 8192

typedef __attribute__((ext_vector_type(8))) __bf16 bf16x8;
typedef __attribute__((ext_vector_type(4))) float  f32x4;
typedef __attribute__((ext_vector_type(4))) int    i32x4;

__device__ __forceinline__ unsigned short f2bf(float f) {
  unsigned int u = __float_as_uint(f);
  u += 0x7fffu + ((u >> 16) & 1u);   // round-to-nearest-even
  return (unsigned short)(u >> 16);
}
__device__ __forceinline__ float bf2f(unsigned int lo16) {
  return __uint_as_float(lo16 << 16);
}

// tanh-form GELU: ~7 VALU instrs vs ~25 for erff; deviation from exact ~1e-3.
__device__ __forceinline__ float fast_gelu(float v) {
  float u = v * (0.79788456080286536f + 0.035677408136300125f * v * v);
  float e = __builtin_amdgcn_exp2f(u * 2.8853900817779268f);   // exp(2u)
  float r = __builtin_amdgcn_rcpf(e + 1.0f);
  return v - v * r;   // = v * e/(e+1) = 0.5 v (1+tanh(u))
}

// ---- async global->LDS, 16B per lane (m97 pattern) ----
__device__ __forceinline__ void gld16(const void* g, void* l) {
  auto* gp = reinterpret_cast<__attribute__((address_space(1))) unsigned int*>(
      reinterpret_cast<uintptr_t>(g));
  auto* lp = reinterpret_cast<__attribute__((address_space(3))) unsigned int*>(
      reinterpret_cast<uintptr_t>(l));
  __builtin_amdgcn_global_load_lds(gp, lp, 16, 0, 0);
}

// ---- wave reduce (two values), 64 lanes, shuffle-only ----
__device__ __forceinline__ void wave_reduce2(float& a, float& b) {
#pragma unroll
  for (int off = 32; off > 0; off >>= 1) {
    a += __shfl_xor(a, off, 64);
    b += __shfl_xor(b, off, 64);
  }
}
__device__ __forceinline__ float wave_reduce_max(float m) {
#pragma unroll
  for (int off = 32; off > 0; off >>= 1) m = fmaxf(m, __shfl_xor(m, off, 64));
  return m;
}

// ---- block reduce (two values), 256 threads = 4 waves ----
__device__ __forceinline__ void block_reduce2(float& a, float& b, int tid) {
  __shared__ float red[8];
  __syncthreads();
  wave_reduce2(a, b);
  if ((tid & 63) == 0) { red[tid >> 6] = a; red[4 + (tid >> 6)] = b; }
  __syncthreads();
  a = red[0] + red[1] + red[2] + red[3];
  b = red[4] + red[5] + red[6] + red[7];
}

// ---- prep: |w| partial sums AND LN1(+i8 quant), one dispatch ----
__global__ __launch_bounds__(256)
void prep_kernel(const float* __restrict__ w1, const float* __restrict__ w2,
                 float* __restrict__ part,
                 const float* __restrict__ x, const float* __restrict__ g,
                 const float* __restrict__ b, unsigned int* __restrict__ xn8,
                 float* __restrict__ invs) {
  int tid = threadIdx.x;
  int bid = blockIdx.x;
  if (bid < 2048) {
    const float* w = (bid < 1024) ? w1 : w2;
    int blk = bid & 1023;
    const float4* base = (const float4*)w + (size_t)blk * 1024;
    float s = 0.f;
#pragma unroll
    for (int i = 0; i < 4; ++i) {
      float4 v = base[tid + i * 256];
      s += fabsf(v.x) + fabsf(v.y) + fabsf(v.z) + fabsf(v.w);
    }
#pragma unroll
    for (int off = 32; off > 0; off >>= 1) s += __shfl_xor(s, off, 64);
    __shared__ float red[4];
    if ((tid & 63) == 0) red[tid >> 6] = s;
    __syncthreads();
    if (tid == 0) part[bid] = red[0] + red[1] + red[2] + red[3];
  } else {
    const int row  = (bid - 2048) * 4 + (tid >> 6);
    const int lane = tid & 63;
    const float4* xr = (const float4*)(x + (size_t)row * DIM);
    const float4* g4 = (const float4*)g;
    const float4* b4 = (const float4*)b;
    float4 v[4];
    float s = 0.f, ss = 0.f;
#pragma unroll
    for (int p = 0; p < 4; ++p) {
      v[p] = xr[lane + 64 * p];
      s  += v[p].x + v[p].y + v[p].z + v[p].w;
      ss += v[p].x * v[p].x + v[p].y * v[p].y + v[p].z * v[p].z + v[p].w * v[p].w;
    }
    wave_reduce2(s, ss);
    float mu  = s * (1.0f / DIM);
    float var = ss * (1.0f / DIM) - mu * mu;
    float rs  = rsqrtf(var + 1e-5f);
    float n[4][4];
    float amax = 0.f;
#pragma unroll
    for (int p = 0; p < 4; ++p) {
      float4 gg = g4[lane + 64 * p];
      float4 bb = b4[lane + 64 * p];
      n[p][0] = (v[p].x - mu) * rs * gg.x + bb.x;
      n[p][1] = (v[p].y - mu) * rs * gg.y + bb.y;
      n[p][2] = (v[p].z - mu) * rs * gg.z + bb.z;
      n[p][3] = (v[p].w - mu) * rs * gg.w + bb.w;
#pragma unroll
      for (int c = 0; c < 4; ++c) amax = fmaxf(amax, fabsf(n[p][c]));
    }
    amax = wave_reduce_max(amax);
    float sc, iv;
    if (amax < 1e-20f) { sc = 0.f; iv = 0.f; }
    else               { sc = 127.0f / amax; iv = amax * (1.0f / 127.0f); }
    if (lane == 0) invs[row] = iv;
    unsigned int* dst = xn8 + (size_t)row * 256;   // 1024 i8 = 256 u32 per row
#pragma unroll
    for (int p = 0; p < 4; ++p) {
      unsigned r = 0;
#pragma unroll
      for (int c = 0; c < 4; ++c) {
        int q = (int)rintf(n[p][c] * sc);
        r |= ((unsigned)q & 0xffu) << (8 * c);
      }
      dst[lane + 64 * p] = r;
    }
  }
}

// ---- ternary quantize + folded-LN2 weight vectors ----
__global__ __launch_bounds__(256)
void quant_kernel(const float* __restrict__ part,
                  const float* __restrict__ w1, unsigned int* __restrict__ q1,
                  const float* __restrict__ w2, unsigned short* __restrict__ q2,
                  const float* __restrict__ g2, const float* __restrict__ b2,
                  const float* __restrict__ bias2,
                  float* __restrict__ Sg, float* __restrict__ Cb,
                  float* __restrict__ scal) {
  int bid = blockIdx.x, tid = threadIdx.x;
  const int lane = tid & 63;
  const float4* psrc = (const float4*)(part + ((bid < 512) ? 0 : 1024));
  float a = 0.f, dummy = 0.f;
#pragma unroll
  for (int p = 0; p < 4; ++p) {
    float4 pv = psrc[lane + 64 * p];
    a += pv.x + pv.y + pv.z + pv.w;
  }
  wave_reduce2(a, dummy);
  float mean = fmaxf(a * (1.0f / 4194304.0f), 1e-5f);
  float sc = 1.0f / mean;

  if (bid < 512) {
    if (bid == 0 && tid == 0) scal[0] = mean;
    const int n4 = 1048576;
    int i = bid * 256 + tid;
    for (; i < n4; i += 512 * 256) {
      float4 v = ((const float4*)w1)[i];
      int t0 = (int)fminf(fmaxf(rintf(v.x * sc), -1.f), 1.f);
      int t1 = (int)fminf(fmaxf(rintf(v.y * sc), -1.f), 1.f);
      int t2 = (int)fminf(fmaxf(rintf(v.z * sc), -1.f), 1.f);
      int t3 = (int)fminf(fmaxf(rintf(v.w * sc), -1.f), 1.f);
      unsigned r = ((unsigned)t0 & 0xffu) | (((unsigned)t1 & 0xffu) << 8) |
                   (((unsigned)t2 & 0xffu) << 16) | (((unsigned)t3 & 0xffu) << 24);
      q1[i] = r;
    }
  } else {
    const int d = bid - 512;
    if (d == 0 && tid == 0) scal[1] = mean;
    const float4* wr = (const float4*)(w2 + (size_t)d * HID);
    const float4* g4 = (const float4*)g2;
    const float4* b4 = (const float4*)b2;
    uint2* qr = (uint2*)(q2 + (size_t)d * HID);
    float s1 = 0.f, s2 = 0.f;
#pragma unroll
    for (int i = 0; i < 4; ++i) {
      int idx = tid + 256 * i;
      float4 wv = wr[idx], gv = g4[idx], bv = b4[idx];
      float t0 = fminf(fmaxf(rintf(wv.x * sc), -1.f), 1.f);
      float t1 = fminf(fmaxf(rintf(wv.y * sc), -1.f), 1.f);
      float t2 = fminf(fmaxf(rintf(wv.z * sc), -1.f), 1.f);
      float t3 = fminf(fmaxf(rintf(wv.w * sc), -1.f), 1.f);
      s1 += gv.x * t0 + gv.y * t1 + gv.z * t2 + gv.w * t3;
      s2 += bv.x * t0 + bv.y * t1 + bv.z * t2 + bv.w * t3;
      uint2 r;
      r.x = (unsigned)f2bf(t0 * gv.x) | ((unsigned)f2bf(t1 * gv.y) << 16);
      r.y = (unsigned)f2bf(t2 * gv.z) | ((unsigned)f2bf(t3 * gv.w) << 16);
      qr[idx] = r;
    }
    block_reduce2(s1, s2, tid);
    if (tid == 0) {
      Sg[d] = mean * s1;
      Cb[d] = mean * s2 + bias2[d];
    }
  }
}

// ---- GEMM1 (i8) v3: dbuf LDS, ONE barrier + ONE vmcnt per K-tile.
// Row-stats fused WITHOUT atomics (R3 post-mortem: 1M device-scope atomicAdds
// with ~1024 collisions/cacheline serialized at the coherent point, +65us,
// +32MB write traffic). Each wave stores its private per-row partial (s,ss)
// as a plain float2 into sbuf2[row][2*col + wn] -- 4MB, no RMW.
__global__ __launch_bounds__(256)
void gemm1_i8(const unsigned char* __restrict__ A,
              const unsigned char* __restrict__ B,
              unsigned short* __restrict__ H,
              const float* __restrict__ wscale_ptr,
              const float* __restrict__ invs,
              const float* __restrict__ bias,
              float2* __restrict__ sbuf2) {
  __shared__ unsigned char sA[2][128 * 64];
  __shared__ unsigned char sB[2][128 * 64];

  const int tid  = threadIdx.x;
  const int lane = tid & 63;
  const int wave = tid >> 6;
  const int wm   = wave & 1;
  const int wn   = wave >> 1;

  const int nbx  = gridDim.x;
  const int id   = blockIdx.y * nbx + blockIdx.x;
  const int xcd  = id & 7;
  const int slot = id >> 3;
  const int bandsPerXcd = gridDim.y >> 3;
  const int band = xcd * bandsPerXcd + slot / nbx;
  const int col  = slot - (slot / nbx) * nbx;
  const int bm   = band * 128;
  const int bn   = col * 128;

  const int csw = ((tid & 3) ^ ((tid >> 3) & 3)) * 16;
  const unsigned char* Ab = A + (size_t)(bm + (tid >> 2)) * 1024 + csw;
  const unsigned char* Bb = B + (size_t)(bn + (tid >> 2)) * 1024 + csw;

  i32x4 acc[4][4] = {};

  const int rowA = (wm * 64 + (lane & 15)) * 64;
  const int rowB = (wn * 64 + (lane & 15)) * 64;
  const int kc = (((lane >> 4) ^ ((lane >> 1) & 3))) * 16;

  // prologue: stage tile 0 -> buf0
  gld16(Ab,             (char*)&sA[0][0] + tid * 16);
  gld16(Ab + 64 * 1024, (char*)&sA[0][0] + 4096 + tid * 16);
  gld16(Bb,             (char*)&sB[0][0] + tid * 16);
  gld16(Bb + 64 * 1024, (char*)&sB[0][0] + 4096 + tid * 16);
  asm volatile("s_waitcnt vmcnt(0)" ::: "memory");
  __builtin_amdgcn_s_barrier();

  for (int t = 0; t < 16; ++t) {
    const int cur = t & 1;
    const size_t kn = (t + 1 < 16) ? (size_t)(t + 1) * 64 : 0;   // clamp = junk, never read
    // 1. issue stage(t+1) -> buf^1 (its old content was consumed before last barrier)
    gld16(Ab + kn,             (char*)&sA[cur ^ 1][0] + tid * 16);
    gld16(Ab + 64 * 1024 + kn, (char*)&sA[cur ^ 1][0] + 4096 + tid * 16);
    gld16(Bb + kn,             (char*)&sB[cur ^ 1][0] + tid * 16);
    gld16(Bb + 64 * 1024 + kn, (char*)&sB[cur ^ 1][0] + 4096 + tid * 16);
    // 2. fragment reads from buf cur (compiler inserts counted lgkm waits)
    const unsigned char* a = &sA[cur][0];
    const unsigned char* b = &sB[cur][0];
    i32x4 af[4], bfr[4];
#pragma unroll
    for (int i = 0; i < 4; ++i) af[i]  = *(const i32x4*)(a + rowA + i * 1024 + kc);
#pragma unroll
    for (int j = 0; j < 4; ++j) bfr[j] = *(const i32x4*)(b + rowB + j * 1024 + kc);
    // 3. MFMA
    __builtin_amdgcn_s_setprio(1);
#pragma unroll
    for (int i = 0; i < 4; ++i)
#pragma unroll
      for (int j = 0; j < 4; ++j)
        acc[i][j] = __builtin_amdgcn_mfma_i32_16x16x64_i8(af[i], bfr[j], acc[i][j], 0, 0, 0);
    __builtin_amdgcn_s_setprio(0);
    // 4. stage(t+1) landed (MFMA span covered latency); release buffers
    asm volatile("s_waitcnt vmcnt(0)" ::: "memory");
    __builtin_amdgcn_s_barrier();
  }

  const float wscale = *wscale_ptr;
  float bv[4];
#pragma unroll
  for (int j = 0; j < 4; ++j) bv[j] = bias[bn + wn * 64 + j * 16 + (lane & 15)];
#pragma unroll
  for (int i = 0; i < 4; ++i) {
    const int m0 = bm + wm * 64 + i * 16 + ((lane >> 4) << 2);
    float asc[4];
#pragma unroll
    for (int r = 0; r < 4; ++r) asc[r] = wscale * invs[m0 + r];
#pragma unroll
    for (int r = 0; r < 4; ++r) {
      float s = 0.f, ss = 0.f;
#pragma unroll
      for (int j = 0; j < 4; ++j) {
        const int n = bn + wn * 64 + j * 16 + (lane & 15);
        float v = fast_gelu((float)acc[i][j][r] * asc[r] + bv[j]);
        H[(size_t)(m0 + r) * HID + n] = f2bf(v);
        s += v; ss += v * v;
      }
      // reduce across the 16 lanes of this hi-group (offsets < 16 stay in group)
#pragma unroll
      for (int off = 1; off < 16; off <<= 1) {
        s  += __shfl_xor(s, off, 64);
        ss += __shfl_xor(ss, off, 64);
      }
      if ((lane & 15) == 0) {
        // private slot, plain store: row (m0+r), column-block slot 2*col + wn
        sbuf2[((size_t)(m0 + r) << 6) + (col << 1) + wn] = make_float2(s, ss);
      }
    }
  }
}

// ---- finalize per-row (a_m, b_m): reduce 64 partials per row ----
__global__ __launch_bounds__(256)
void murs_fin(const float2* __restrict__ sbuf2, const float* __restrict__ meanp,
              float2* __restrict__ murs) {
  const int row  = blockIdx.x * 4 + (threadIdx.x >> 6);
  const int lane = threadIdx.x & 63;
  float2 v = sbuf2[((size_t)row << 6) + lane];
  float s = v.x, ss = v.y;
  wave_reduce2(s, ss);
  if (lane == 0) {
    float mu  = s * (1.0f / HID);
    float var = ss * (1.0f / HID) - mu * mu;
    float rs  = rsqrtf(var + 1e-5f);
    murs[row] = make_float2(rs * meanp[1], -rs * mu);
  }
}

// ---- GEMM2 v3: dbuf bf16, ONE barrier + ONE vmcnt(0) per K-tile ----
// (unchanged from R3 -- dropped out of top-5 there, i.e. < 137us; need its
// counters to show up cleanly this round to know its true cost)
__global__ __launch_bounds__(512, 2)
void gemm2_v3(const unsigned short* __restrict__ A,
              const unsigned short* __restrict__ B,
              float* __restrict__ C,
              const float2* __restrict__ murs,
              const float* __restrict__ Sg,
              const float* __restrict__ Cb) {
  __shared__ unsigned short sA[2][256 * 64];
  __shared__ unsigned short sB[2][128 * 64];

  const int tid  = threadIdx.x;
  const int lane = tid & 63;
  const int wave = tid >> 6;
  const int wm   = wave >> 1;    // 0..3
  const int wn   = wave & 1;     // 0..1

  // XCD-aware remap: 256 blocks (32 bands x 8 cols), 4 bands/XCD. Bijective.
  const int id   = blockIdx.y * 8 + blockIdx.x;
  const int xcd  = id & 7;
  const int slot = id >> 3;
  const int band = xcd * 4 + (slot >> 3);
  const int col  = slot & 7;
  const int bm   = band * 256;
  const int bn   = col * 128;

  // staging: linear LDS dest + pre-swizzled global source (rule #21)
  const int csw = ((tid & 7) ^ ((tid >> 3) & 7)) << 3;     // elements
  const unsigned short* Ab = A + (size_t)(bm + (tid >> 3)) * 4096 + csw;
  const unsigned short* Bb = B + (size_t)(bn + (tid >> 3)) * 4096 + csw;

  // fragment reads: row = wbase + frag*16 + (lane&15); phys chunk = log ^ (lane&7)
  const int rowAb = (wm * 64 + (lane & 15)) * 128;   // bytes
  const int rowBb = (wn * 64 + (lane & 15)) * 128;
  const int hi    = lane >> 4;
  const int ck0   = ((hi)     ^ (lane & 7)) << 4;    // k-slice 0, bytes
  const int ck1   = ((hi + 4) ^ (lane & 7)) << 4;    // k-slice 1

  f32x4 acc[4][4] = {};

  // prologue: stage tile 0 -> buf0
#pragma unroll
  for (int i = 0; i < 4; ++i) gld16(Ab + (size_t)i * 262144, (char*)&sA[0][0] + i * 8192 + tid * 16);
#pragma unroll
  for (int i = 0; i < 2; ++i) gld16(Bb + (size_t)i * 262144, (char*)&sB[0][0] + i * 8192 + tid * 16);
  asm volatile("s_waitcnt vmcnt(0)" ::: "memory");
  __builtin_amdgcn_s_barrier();

  for (int t = 0; t < 64; ++t) {
    const int cur = t & 1;
    const size_t kn = (t + 1 < 64) ? (size_t)(t + 1) * 64 : 0;   // clamp = junk, never read
    // 1. issue stage(t+1) -> buf^1 (consumed before the barrier we just passed)
#pragma unroll
    for (int i = 0; i < 4; ++i)
      gld16(Ab + (size_t)i * 262144 + kn, (char*)&sA[cur ^ 1][0] + i * 8192 + tid * 16);
#pragma unroll
    for (int i = 0; i < 2; ++i)
      gld16(Bb + (size_t)i * 262144 + kn, (char*)&sB[cur ^ 1][0] + i * 8192 + tid * 16);
    // 2. all 16 fragment reads from buf cur
    const char* a = (const char*)&sA[cur][0];
    const char* b = (const char*)&sB[cur][0];
    bf16x8 af[4][2], bfr[4][2];
#pragma unroll
    for (int i = 0; i < 4; ++i) {
      af[i][0] = *(const bf16x8*)(a + rowAb + i * 2048 + ck0);
      af[i][1] = *(const bf16x8*)(a + rowAb + i * 2048 + ck1);
    }
#pragma unroll
    for (int j = 0; j < 4; ++j) {
      bfr[j][0] = *(const bf16x8*)(b + rowBb + j * 2048 + ck0);
      bfr[j][1] = *(const bf16x8*)(b + rowBb + j * 2048 + ck1);
    }
    // 3. 32 MFMA, k-slice 0 cluster first (waits only the first half of reads)
    __builtin_amdgcn_s_setprio(1);
#pragma unroll
    for (int i = 0; i < 4; ++i)
#pragma unroll
      for (int j = 0; j < 4; ++j)
        acc[i][j] = __builtin_amdgcn_mfma_f32_16x16x32_bf16(af[i][0], bfr[j][0], acc[i][j], 0, 0, 0);
#pragma unroll
    for (int i = 0; i < 4; ++i)
#pragma unroll
      for (int j = 0; j < 4; ++j)
        acc[i][j] = __builtin_amdgcn_mfma_f32_16x16x32_bf16(af[i][1], bfr[j][1], acc[i][j], 0, 0, 0);
    __builtin_amdgcn_s_setprio(0);
    // 4. stage(t+1) landed (MFMA span covered latency); release buffers
    asm volatile("s_waitcnt vmcnt(0)" ::: "memory");
    __builtin_amdgcn_s_barrier();
  }

  // ---- epilogue: out = a_m*acc + b_m*Sg[n] + Cb[n]
  float sg[4], cb[4];
#pragma unroll
  for (int j = 0; j < 4; ++j) {
    const int n = bn + wn * 64 + j * 16 + (lane & 15);
    sg[j] = Sg[n];
    cb[j] = Cb[n];
  }
#pragma unroll
  for (int i = 0; i < 4; ++i) {
    const int m0 = bm + wm * 64 + i * 16 + (hi << 2);
#pragma unroll
    for (int r = 0; r < 4; ++r) {
      float2 ab = murs[m0 + r];
#pragma unroll
      for (int j = 0; j < 4; ++j) {
        const int n = bn + wn * 64 + j * 16 + (lane & 15);
        C[(size_t)(m0 + r) * 1024 + n] = ab.x * acc[i][j][r] + ab.y * sg[j] + cb[j];
      }
    }
  }
}

extern "C" void kernel_launch(void* const* d_in, const int* in_sizes, int n_in,
                              void* d_out, int out_size, void* d_ws, size_t ws_size,
                              hipStream_t stream) {
  const float* x     = (const float*)d_in[0];
  const float* g1    = (const float*)d_in[1];
  const float* b1v   = (const float*)d_in[2];
  const float* w1    = (const float*)d_in[3];
  const float* bias1 = (const float*)d_in[4];
  const float* g2    = (const float*)d_in[5];
  const float* b2v   = (const float*)d_in[6];
  const float* w2    = (const float*)d_in[7];
  const float* bias2 = (const float*)d_in[8];
  float* out = (float*)d_out;

  char* ws = (char*)d_ws;
  float* scal          = (float*)ws;                      // [0]=mean|w1| [1]=mean|w2|
  float* part          = (float*)(ws + 64);               // 2048 partials
  float* invs          = (float*)(ws + 16384);            // 8192 per-row dequant (32 KB)
  unsigned int* q1     = (unsigned int*)(ws + 65536);     // 4096x1024 i8 = 4 MB
  unsigned short* q2   = (unsigned short*)(ws + 65536 + 4194304);  // 8 MB bf16
  unsigned int* xn8    = (unsigned int*)((char*)q2 + 8388608);     // 8192x1024 i8 = 8 MB
  unsigned short* h    = (unsigned short*)((char*)xn8 + 8388608);  // 64 MB bf16
  float2* murs         = (float2*)((char*)h + 67108864);  // 8192 x {a_m,b_m}
  float* Sg            = (float*)(murs + 8192);           // 1024
  float* Cb            = Sg + 1024;                       // 1024
  float2* sbuf2        = (float2*)(Cb + 1024);            // 8192 x 64 partials = 4 MB

  prep_kernel<<<4096, 256, 0, stream>>>(w1, w2, part, x, g1, b1v, xn8, invs);
  quant_kernel<<<1536, 256, 0, stream>>>(part, w1, q1, w2, q2, g2, b2v, bias2, Sg, Cb, scal);
  gemm1_i8<<<dim3(HID / 128, MROWS / 128), 256, 0, stream>>>(
      (const unsigned char*)xn8, (const unsigned char*)q1, h, scal + 0, invs, bias1, sbuf2);
  murs_fin<<<MROWS / 4, 256, 0, stream>>>(sbuf2, scal, murs);
  gemm2_v3<<<dim3(8, 32), 512, 0, stream>>>(h, q2, out, murs, Sg, Cb);
}